// Round 9
// baseline (217.352 us; speedup 1.0000x reference)
//
#include <hip/hip_runtime.h>
#include <stdint.h>

// Fused attention head: out = softmax(mask((Tgt@Wq)(Src@Wk)^T * H^-0.5)) @ (Src@Wv)
// B=4096, T=128, C=128, H=64. One block/batch, 512 threads (8 waves).
// R9: EMB staging deleted — MFMA A-frags load directly from global (lane's
// 8-float span = the frag's k-span), f32->bf16 via compiler __bf16 casts.
// LDS = Kb+Vb+BIAS = 32.5KB -> 4 blocks/CU (32 waves, 100% occ at VGPR<=64).
// ONE barrier. Tail (shuffle redistribution, softmax, PV) = R8, proven.

typedef uint32_t u32x2 __attribute__((ext_vector_type(2)));
typedef uint32_t u32x4 __attribute__((ext_vector_type(4)));
typedef float    f32x4 __attribute__((ext_vector_type(4)));
typedef __bf16   bf16x8 __attribute__((ext_vector_type(8)));

static __device__ __forceinline__ uint32_t pack2(float a, float b) {  // RNE (prep kernel)
  uint32_t ua = __builtin_bit_cast(uint32_t, a);
  uint32_t ub = __builtin_bit_cast(uint32_t, b);
  ua += 0x7FFFu + ((ua >> 16) & 1u);
  ub += 0x7FFFu + ((ub >> 16) & 1u);
  return (ua >> 16) | (ub & 0xFFFF0000u);
}
// compiler-generated f32->bf16 (RNE fptrunc); cheap and semantically guaranteed
static __device__ __forceinline__ uint32_t cvt2(float a, float b) {
  uint16_t lo = __builtin_bit_cast(uint16_t, (__bf16)a);
  uint16_t hi = __builtin_bit_cast(uint16_t, (__bf16)b);
  return (uint32_t)lo | ((uint32_t)hi << 16);
}
static __device__ __forceinline__ f32x4 mfma16(u32x4 a, u32x4 b, f32x4 c) {
  return __builtin_amdgcn_mfma_f32_16x16x32_bf16(
      __builtin_bit_cast(bf16x8, a), __builtin_bit_cast(bf16x8, b), c, 0, 0, 0);
}

// ---- prep: pack Wq/Wk/Wv into MFMA frag layout in ws; detect mask dtype ----
// frag f=(m*4+ct)*4+ks, lane l: 8 bf16 of W[c][h], h=ct*16+(l&15), c=ks*32+(l>>4)*8+0..7.
// Serves BOTH as B-frag of W (V proj) and A-frag of W^T (K/Q proj).
__global__ void prep_w(const float* __restrict__ Wq, const float* __restrict__ Wk,
                       const float* __restrict__ Wv, const void* __restrict__ mask,
                       uint32_t* __restrict__ ws) {
  const int blk = blockIdx.x;
  const int l = threadIdx.x;  // 0..63
  if (blk < 48) {
    const int m  = blk >> 4;
    const int ct = (blk >> 2) & 3;
    const int ks = blk & 3;
    const float* W = (m == 0) ? Wq : ((m == 1) ? Wk : Wv);
    const int h  = ct * 16 + (l & 15);
    const int c0 = ks * 32 + (l >> 4) * 8;
    u32x4 v;
#pragma unroll
    for (int p = 0; p < 4; ++p)
      v[p] = pack2(W[(c0 + 2 * p) * 64 + h], W[(c0 + 2 * p + 1) * 64 + h]);
    ((u32x4*)ws)[blk * 64 + l] = v;
  } else {
    // mask dtype detect: 0=int32(0/1), 1=bytes, 2=float
    const uint32_t* mw = (const uint32_t*)mask;
    int fl = 0;
    for (int i = l * 16; i < l * 16 + 16; ++i) {
      uint32_t x = mw[i];
      if (x == 0x3F800000u) fl = 2;
      else if (x > 1u && fl != 2) fl = 1;
    }
#pragma unroll
    for (int off = 32; off > 0; off >>= 1) {
      int o = __shfl_down(fl, off);
      fl = (o > fl) ? o : fl;
    }
    if (l == 0) ws[12288] = (uint32_t)fl;
  }
}

// LDS (32.5 KB -> 4 blocks/CU):
//  Kb  [128][64] bf16 swz (16K)  K[s][h]
//  Vb  [64][128] bf16 swz (16K)  V^T[h][s]
//  BIAS[128] f32
// Swizzle: 16B chunk c of row r stored at chunk (c ^ (r&7)).
__global__ __launch_bounds__(512, 4) void attn_fused(
    const float* __restrict__ src, const float* __restrict__ tgt,
    const void* __restrict__ mask, const uint32_t* __restrict__ ws,
    float* __restrict__ out) {
  __shared__ __align__(16) uint8_t lds[33280];
  uint8_t* const Kb  = lds;
  uint8_t* const Vb  = lds + 16384;
  float*  const BIAS = (float*)(lds + 32768);

  const int b   = blockIdx.x;
  const int tid = (int)threadIdx.x;
  const int l   = tid & 63;
  const int w   = tid >> 6;      // wave 0..7
  const int l15 = l & 15;
  const int g4  = l >> 4;        // 0..3
  const int ct  = w & 3;         // wave's h-tile for K/V projections
  const int sg  = (w >> 2) * 4;  // wave's first s-tile (0 or 4) — 4 tiles/wave

  const u32x4* wsv = (const u32x4*)ws;
  const int mflag = (int)ws[12288];
  const float* const srcb = src + (size_t)b * 16384;
  const float* const tgtb = tgt + (size_t)b * 16384;

  // pad-mask bias (one barrier covers this write + K/V writes)
  if (tid < 128) {
    bool valid;
    if (mflag == 1)      valid = ((const uint8_t*)mask)[b * 128 + tid] != 0;
    else if (mflag == 0) valid = ((const int*)mask)[b * 128 + tid] != 0;
    else                 valid = ((const float*)mask)[b * 128 + tid] != 0.0f;
    BIAS[tid] = valid ? 0.0f : -1e30f;
  }

  // ---- projKV: K = Src@Wk (-> K[s][h]), V = Src@Wv (-> V^T[h][s]) ----
  // ks-outer / tile-inner keeps live regs ~56: W frags of current ks (8) +
  // 8 accumulators (32) + A-frag transients. A-frag loaded straight from
  // global: lane (g4,l15) needs src[row = st*16+l15][ks*32+g4*8 .. +7].
  f32x4 cK[4], cV[4];
#pragma unroll
  for (int i = 0; i < 4; ++i) { cK[i] = {0,0,0,0}; cV[i] = {0,0,0,0}; }
#pragma unroll
  for (int ks = 0; ks < 4; ++ks) {
    const u32x4 wkf = wsv[((4 + ct) * 4 + ks) * 64 + l];  // A-frag of Wk^T
    const u32x4 wvf = wsv[((8 + ct) * 4 + ks) * 64 + l];  // B-frag of Wv
#pragma unroll
    for (int i = 0; i < 4; ++i) {
      const int row = (sg + i) * 16 + l15;
      const float* pa = srcb + row * 128 + ks * 32 + g4 * 8;
      f32x4 a0 = *(const f32x4*)pa;
      f32x4 a1 = *(const f32x4*)(pa + 4);
      u32x4 e = { cvt2(a0[0], a0[1]), cvt2(a0[2], a0[3]),
                  cvt2(a1[0], a1[1]), cvt2(a1[2], a1[3]) };
      cK[i] = mfma16(wkf, e, cK[i]);   // C[h][s]
      cV[i] = mfma16(e, wvf, cV[i]);   // C[s][h]
    }
  }
#pragma unroll
  for (int i = 0; i < 4; ++i) {
    const int st = sg + i;
    const int s  = st * 16 + l15;                    // K: n=s per-lane col
    const int h0 = ct * 16 + g4 * 4;                 //    m=h rows (packed pair-write)
    u32x2 dk = { cvt2(cK[i][0], cK[i][1]), cvt2(cK[i][2], cK[i][3]) };
    *(u32x2*)(Kb + (s << 7) + ((((h0 >> 3) ^ (s & 7))) << 4) + ((h0 & 7) << 1)) = dk;
    const int s0 = st * 16 + g4 * 4;                 // V^T: m=s packed, n=h col
    const int h  = ct * 16 + l15;
    u32x2 dv = { cvt2(cV[i][0], cV[i][1]), cvt2(cV[i][2], cV[i][3]) };
    *(u32x2*)(Vb + (h << 8) + ((((s0 >> 3) ^ (h & 7))) << 4) + ((s0 & 7) << 1)) = dv;
  }

  // ---- projQ (consumer-aligned): wave w computes Q^T for ITS OWN t-tile ----
  // (t = 16w + l15), all 64 h (4 ct tiles); Wq A-frags streamed from L2.
  // qp[ctq*2+p] = bf16x2 of Q^T[h = ctq*16 + g4*4 + 2p + {0,1}][t].
  uint32_t qp[8];
  {
    const float* pq = tgtb + (16 * w + l15) * 128;
    f32x4 c0 = {0,0,0,0}, c1 = {0,0,0,0}, c2 = {0,0,0,0}, c3 = {0,0,0,0};
#pragma unroll
    for (int ks = 0; ks < 4; ++ks) {
      const float* pa = pq + ks * 32 + g4 * 8;
      f32x4 a0 = *(const f32x4*)pa;
      f32x4 a1 = *(const f32x4*)(pa + 4);
      u32x4 e = { cvt2(a0[0], a0[1]), cvt2(a0[2], a0[3]),
                  cvt2(a1[0], a1[1]), cvt2(a1[2], a1[3]) };
      c0 = mfma16(wsv[(0  + ks) * 64 + l], e, c0);
      c1 = mfma16(wsv[(4  + ks) * 64 + l], e, c1);
      c2 = mfma16(wsv[(8  + ks) * 64 + l], e, c2);
      c3 = mfma16(wsv[(12 + ks) * 64 + l], e, c3);
    }
    qp[0] = cvt2(c0[0], c0[1]); qp[1] = cvt2(c0[2], c0[3]);
    qp[2] = cvt2(c1[0], c1[1]); qp[3] = cvt2(c1[2], c1[3]);
    qp[4] = cvt2(c2[0], c2[1]); qp[5] = cvt2(c2[2], c2[3]);
    qp[6] = cvt2(c3[0], c3[1]); qp[7] = cvt2(c3[2], c3[3]);
  }

  __syncthreads();  // THE barrier: Kb/Vb/BIAS visible block-wide

  // ---- C-frag -> B-frag redistribution (double-pull + consumer-side select) ----
  // Consumer (g4,l15) word m of step ks needs h(s) = ks*32+g4*8+2m+{0,1}, held
  // by producer lane (2*(g4&1)+(m>>1))*16+l15 in word [4ks + 2*(g4>>1)+(m&1)].
  const int hi2 = g4 >> 1;
  const int sA  = ((g4 & 1) * 2) * 16 + l15;  // src lane for words m=0,1
  const int sB  = sA + 16;                    // src lane for words m=2,3

  u32x4 qB[2];
#pragma unroll
  for (int ks = 0; ks < 2; ++ks) {
    uint32_t a0 = (uint32_t)__shfl((int)qp[4 * ks + 0], sA);
    uint32_t a1 = (uint32_t)__shfl((int)qp[4 * ks + 1], sA);
    uint32_t a2 = (uint32_t)__shfl((int)qp[4 * ks + 2], sA);
    uint32_t a3 = (uint32_t)__shfl((int)qp[4 * ks + 3], sA);
    uint32_t b0 = (uint32_t)__shfl((int)qp[4 * ks + 0], sB);
    uint32_t b1 = (uint32_t)__shfl((int)qp[4 * ks + 1], sB);
    uint32_t b2 = (uint32_t)__shfl((int)qp[4 * ks + 2], sB);
    uint32_t b3 = (uint32_t)__shfl((int)qp[4 * ks + 3], sB);
    qB[ks][0] = hi2 ? a2 : a0;
    qB[ks][1] = hi2 ? a3 : a1;
    qB[ks][2] = hi2 ? b2 : b0;
    qB[ks][3] = hi2 ? b3 : b1;
  }

  // ---- S^T = K @ Q^T : per lane col t = 16w+l15, rows s = mt*16+g4*4+r ----
  const int tq = 16 * w + l15;
  f32x4 sacc[8];
#pragma unroll
  for (int mt = 0; mt < 8; ++mt) sacc[mt] = {0, 0, 0, 0};
  __builtin_amdgcn_s_setprio(1);
#pragma unroll
  for (int mt = 0; mt < 8; ++mt) {
    const int srow = mt * 16 + l15;
    u32x4 k0 = *(const u32x4*)(Kb + (srow << 7) + (((g4 ^ (srow & 7))) << 4));
    u32x4 k1 = *(const u32x4*)(Kb + (srow << 7) + ((((4 + g4) ^ (srow & 7))) << 4));
    sacc[mt] = mfma16(k0, qB[0], sacc[mt]);
    sacc[mt] = mfma16(k1, qB[1], sacc[mt]);
  }
  __builtin_amdgcn_s_setprio(0);

  // ---- softmax over s (32 s-values/lane; reduce across 4-lane group) ----
  float m = -3.0e38f;
#pragma unroll
  for (int mt = 0; mt < 8; ++mt) {
    f32x4 b4 = *(const f32x4*)(BIAS + mt * 16 + g4 * 4);
#pragma unroll
    for (int r = 0; r < 4; ++r) {
      float v = sacc[mt][r] * 0.125f + b4[r];  // scale = H^-0.5 ; pad bias -1e30
      sacc[mt][r] = v;
      m = fmaxf(m, v);
    }
  }
  m = fmaxf(m, __shfl_xor(m, 16));
  m = fmaxf(m, __shfl_xor(m, 32));
  float sum = 0.0f;
#pragma unroll
  for (int mt = 0; mt < 8; ++mt) {
#pragma unroll
    for (int r = 0; r < 4; ++r) {
      const int s = mt * 16 + g4 * 4 + r;
      float p = __expf(sacc[mt][r] - m);
      p = (s <= tq) ? p : 0.0f;               // causal, multiplicative
      sacc[mt][r] = p;
      sum += p;
    }
  }
  sum += __shfl_xor(sum, 16);
  sum += __shfl_xor(sum, 32);
  const float inv = 1.0f / sum;  // >0: col 0 always valid & causal-visible

  // pack P (unnormalized, <=1): sp[2mt+p] = bf16x2 of P^T[s=mt*16+g4*4+2p+{0,1}][t]
  uint32_t sp[16];
#pragma unroll
  for (int mt = 0; mt < 8; ++mt) {
    sp[2 * mt]     = cvt2(sacc[mt][0], sacc[mt][1]);
    sp[2 * mt + 1] = cvt2(sacc[mt][2], sacc[mt][3]);
  }

  // ---- OUT^T = V^T @ P^T : A = V^T from Vb rows, B = P via shuffles ----
  f32x4 oacc[4];
#pragma unroll
  for (int vt = 0; vt < 4; ++vt) oacc[vt] = {0, 0, 0, 0};
  __builtin_amdgcn_s_setprio(1);
#pragma unroll
  for (int ks = 0; ks < 4; ++ks) {
    uint32_t a0 = (uint32_t)__shfl((int)sp[4 * ks + 0], sA);
    uint32_t a1 = (uint32_t)__shfl((int)sp[4 * ks + 1], sA);
    uint32_t a2 = (uint32_t)__shfl((int)sp[4 * ks + 2], sA);
    uint32_t a3 = (uint32_t)__shfl((int)sp[4 * ks + 3], sA);
    uint32_t b0 = (uint32_t)__shfl((int)sp[4 * ks + 0], sB);
    uint32_t b1 = (uint32_t)__shfl((int)sp[4 * ks + 1], sB);
    uint32_t b2 = (uint32_t)__shfl((int)sp[4 * ks + 2], sB);
    uint32_t b3 = (uint32_t)__shfl((int)sp[4 * ks + 3], sB);
    u32x4 pb;
    pb[0] = hi2 ? a2 : a0;
    pb[1] = hi2 ? a3 : a1;
    pb[2] = hi2 ? b2 : b0;
    pb[3] = hi2 ? b3 : b1;
#pragma unroll
    for (int vt = 0; vt < 4; ++vt) {
      const int vrow = vt * 16 + l15;
      u32x4 vf = *(const u32x4*)(Vb + (vrow << 8) + ((((ks * 4 + g4) ^ (vrow & 7))) << 4));
      oacc[vt] = mfma16(vf, pb, oacc[vt]);
    }
  }
  __builtin_amdgcn_s_setprio(0);

  // epilogue: out[t][h], t = 16w + l15, h = vt*16 + g4*4 + r ; fold 1/sum
  float* const ob = out + (size_t)b * 8192 + (size_t)tq * 64;
#pragma unroll
  for (int vt = 0; vt < 4; ++vt) {
    f32x4 o = { oacc[vt][0] * inv, oacc[vt][1] * inv,
                oacc[vt][2] * inv, oacc[vt][3] * inv };
    *(f32x4*)(ob + vt * 16 + g4 * 4) = o;
  }
}

extern "C" void kernel_launch(void* const* d_in, const int* in_sizes, int n_in,
                              void* d_out, int out_size, void* d_ws, size_t ws_size,
                              hipStream_t stream) {
  const float* src = (const float*)d_in[0];
  const float* tgt = (const float*)d_in[1];
  const void*  msk = d_in[2];
  const float* Wq  = (const float*)d_in[3];
  const float* Wk  = (const float*)d_in[4];
  const float* Wv  = (const float*)d_in[5];
  uint32_t* ws = (uint32_t*)d_ws;  // 48KB W frags + mask-dtype flag
  float* out = (float*)d_out;
  const int B = in_sizes[0] / (128 * 128);

  hipLaunchKernelGGL(prep_w, dim3(49), dim3(64), 0, stream, Wq, Wk, Wv, msk, ws);
  hipLaunchKernelGGL(attn_fused, dim3(B), dim3(512), 0, stream,
                     src, tgt, msk, ws, out);
}

// Round 10
// 154.133 us; speedup vs baseline: 1.4102x; 1.4102x over previous
//
#include <hip/hip_runtime.h>
#include <stdint.h>

// Fused attention head: out = softmax(mask((Tgt@Wq)(Src@Wk)^T * H^-0.5)) @ (Src@Wv)
// B=4096, T=128, C=128, H=64. One block/batch, 512 threads (8 waves).
// R10 hybrid of measured-best parts:
//  - K/V: R5's EMB-staged pipeline (coalesced, 2 phases, 4 barriers total)
//  - Q: consumer-aligned from GLOBAL (wave reads its own 16 tgt rows once,
//    issued first = longest latency first; all waves symmetric, no R8 split)
//  - tail: R8 verbatim (register Q/P + double-pull shuffle redistribution)
// LDS 48.5KB (Qb deleted); no P LDS bounce; no tgt staging.

typedef uint32_t u32x2 __attribute__((ext_vector_type(2)));
typedef uint32_t u32x4 __attribute__((ext_vector_type(4)));
typedef float    f32x4 __attribute__((ext_vector_type(4)));
typedef __bf16   bf16x8 __attribute__((ext_vector_type(8)));

static __device__ __forceinline__ uint32_t pack2(float a, float b) {  // RNE (prep kernel)
  uint32_t ua = __builtin_bit_cast(uint32_t, a);
  uint32_t ub = __builtin_bit_cast(uint32_t, b);
  ua += 0x7FFFu + ((ua >> 16) & 1u);
  ub += 0x7FFFu + ((ub >> 16) & 1u);
  return (ua >> 16) | (ub & 0xFFFF0000u);
}
// compiler-generated f32->bf16 RNE pair (HW-proven R9: PASS, absmax 5.9e-3)
static __device__ __forceinline__ uint32_t cvt2(float a, float b) {
  uint16_t lo = __builtin_bit_cast(uint16_t, (__bf16)a);
  uint16_t hi = __builtin_bit_cast(uint16_t, (__bf16)b);
  return (uint32_t)lo | ((uint32_t)hi << 16);
}
static __device__ __forceinline__ f32x4 mfma16(u32x4 a, u32x4 b, f32x4 c) {
  return __builtin_amdgcn_mfma_f32_16x16x32_bf16(
      __builtin_bit_cast(bf16x8, a), __builtin_bit_cast(bf16x8, b), c, 0, 0, 0);
}

// ---- prep: pack Wq/Wk/Wv into MFMA frag layout in ws; detect mask dtype ----
// frag f=(m*4+ct)*4+ks, lane l: 8 bf16 of W[c][h], h=ct*16+(l&15), c=ks*32+(l>>4)*8+0..7.
// Serves BOTH as B-frag of W (V proj) and A-frag of W^T (K/Q proj).
__global__ void prep_w(const float* __restrict__ Wq, const float* __restrict__ Wk,
                       const float* __restrict__ Wv, const void* __restrict__ mask,
                       uint32_t* __restrict__ ws) {
  const int blk = blockIdx.x;
  const int l = threadIdx.x;  // 0..63
  if (blk < 48) {
    const int m  = blk >> 4;
    const int ct = (blk >> 2) & 3;
    const int ks = blk & 3;
    const float* W = (m == 0) ? Wq : ((m == 1) ? Wk : Wv);
    const int h  = ct * 16 + (l & 15);
    const int c0 = ks * 32 + (l >> 4) * 8;
    u32x4 v;
#pragma unroll
    for (int p = 0; p < 4; ++p)
      v[p] = pack2(W[(c0 + 2 * p) * 64 + h], W[(c0 + 2 * p + 1) * 64 + h]);
    ((u32x4*)ws)[blk * 64 + l] = v;
  } else {
    // mask dtype detect: 0=int32(0/1), 1=bytes, 2=float
    const uint32_t* mw = (const uint32_t*)mask;
    int fl = 0;
    for (int i = l * 16; i < l * 16 + 16; ++i) {
      uint32_t x = mw[i];
      if (x == 0x3F800000u) fl = 2;
      else if (x > 1u && fl != 2) fl = 1;
    }
#pragma unroll
    for (int off = 32; off > 0; off >>= 1) {
      int o = __shfl_down(fl, off);
      fl = (o > fl) ? o : fl;
    }
    if (l == 0) ws[12288] = (uint32_t)fl;
  }
}

// LDS (48.5 KB):
//  EMB [64][128] bf16 swz (16K)  src staging (2 halves, reused)
//  Kb  [128][64] bf16 swz (16K)  K[s][h]
//  Vb  [64][128] bf16 swz (16K)  V^T[h][s]
//  BIAS[128] f32
// Swizzle: 16B chunk c of row r stored at chunk (c ^ (r&7)).
__global__ __launch_bounds__(512, 3) void attn_fused(
    const float* __restrict__ src, const float* __restrict__ tgt,
    const void* __restrict__ mask, const uint32_t* __restrict__ ws,
    float* __restrict__ out) {
  __shared__ __align__(16) uint8_t lds[49664];
  uint8_t* const EMB = lds;
  uint8_t* const Kb  = lds + 16384;
  uint8_t* const Vb  = lds + 32768;
  float*  const BIAS = (float*)(lds + 49152);

  const int b   = blockIdx.x;
  const int tid = (int)threadIdx.x;
  const int l   = tid & 63;
  const int w   = tid >> 6;      // wave 0..7
  const int l15 = l & 15;
  const int g4  = l >> 4;        // 0..3
  const int ct  = w & 3;         // wave's h-tile for K/V projections
  const int sg  = (w >> 2) * 2;  // wave's first local row-tile for K/V (0 or 2)
  const int tq  = 16 * w + l15;  // this lane's output row t

  const u32x4* wsv = (const u32x4*)ws;
  const int mflag = (int)ws[12288];
  const float* const srcb = src + (size_t)b * 16384;
  const float* const tgtb = tgt + (size_t)b * 16384;

  // ---- issue longest-latency loads FIRST ----
  // Q A-frag rows: lane needs tgt[tq][ks*32 + g4*8 + 0..7] for ks=0..3
  f32x4 qv[8];
  {
    const float* pq = tgtb + tq * 128 + g4 * 8;
#pragma unroll
    for (int ks = 0; ks < 4; ++ks) {
      qv[2 * ks]     = *(const f32x4*)(pq + ks * 32);
      qv[2 * ks + 1] = *(const f32x4*)(pq + ks * 32 + 4);
    }
  }
  // src half A staging loads
  f32x4 pf[4];
  auto stage_load = [&](const float* gbase) {
#pragma unroll
    for (int p = 0; p < 4; ++p)
      pf[p] = *(const f32x4*)(gbase + tid * 4 + p * 2048);
  };
  stage_load(srcb);
  // pad-mask bias
  float biasv = 0.0f;
  if (tid < 128) {
    bool valid;
    if (mflag == 1)      valid = ((const uint8_t*)mask)[b * 128 + tid] != 0;
    else if (mflag == 0) valid = ((const int*)mask)[b * 128 + tid] != 0;
    else                 valid = ((const float*)mask)[b * 128 + tid] != 0.0f;
    biasv = valid ? 0.0f : -1e30f;
  }

  // ---- projQ (consumer-aligned, from global): all 64 h for own t-tile ----
  // qp[ctq*2+p] = bf16x2 of Q^T[h = ctq*16 + g4*4 + 2p + {0,1}][t]
  uint32_t qp[8];
  {
    f32x4 c0 = {0,0,0,0}, c1 = {0,0,0,0}, c2 = {0,0,0,0}, c3 = {0,0,0,0};
#pragma unroll
    for (int ks = 0; ks < 4; ++ks) {
      u32x4 e = { cvt2(qv[2*ks][0], qv[2*ks][1]), cvt2(qv[2*ks][2], qv[2*ks][3]),
                  cvt2(qv[2*ks+1][0], qv[2*ks+1][1]), cvt2(qv[2*ks+1][2], qv[2*ks+1][3]) };
      c0 = mfma16(wsv[(0  + ks) * 64 + l], e, c0);
      c1 = mfma16(wsv[(4  + ks) * 64 + l], e, c1);
      c2 = mfma16(wsv[(8  + ks) * 64 + l], e, c2);
      c3 = mfma16(wsv[(12 + ks) * 64 + l], e, c3);
    }
    qp[0] = cvt2(c0[0], c0[1]); qp[1] = cvt2(c0[2], c0[3]);
    qp[2] = cvt2(c1[0], c1[1]); qp[3] = cvt2(c1[2], c1[3]);
    qp[4] = cvt2(c2[0], c2[1]); qp[5] = cvt2(c2[2], c2[3]);
    qp[6] = cvt2(c3[0], c3[1]); qp[7] = cvt2(c3[2], c3[3]);
  }

  // ---- staged K/V pipeline (R5 structure, src only) ----
  auto stage_write = [&]() {
#pragma unroll
    for (int p = 0; p < 4; ++p) {
      const int c   = tid + p * 512;
      const int row = c >> 5;     // 0..63
      const int cc  = c & 31;     // f32x4 chunk within row
      u32x2 d = { cvt2(pf[p][0], pf[p][1]), cvt2(pf[p][2], pf[p][3]) };
      *(u32x2*)(EMB + (row << 8) + ((((cc >> 1) ^ (row & 7))) << 4) + ((cc & 1) << 3)) = d;
    }
  };
  u32x4 wk[4], wv[4];
#pragma unroll
  for (int ks = 0; ks < 4; ++ks) {
    wk[ks] = wsv[((4 + ct) * 4 + ks) * 64 + l];   // A-frag of Wk^T
    wv[ks] = wsv[((8 + ct) * 4 + ks) * 64 + l];   // B-frag of Wv
  }
  auto projKV = [&](int half) {
#pragma unroll
    for (int i = 0; i < 2; ++i) {
      const int st  = sg + i;            // local 16-row tile 0..3
      const int row = st * 16 + l15;     // EMB row
      f32x4 cK = {0, 0, 0, 0}, cV = {0, 0, 0, 0};
#pragma unroll
      for (int ks = 0; ks < 4; ++ks) {
        u32x4 e = *(const u32x4*)(EMB + (row << 8) + ((((ks * 4 + g4) ^ (row & 7))) << 4));
        cK = mfma16(wk[ks], e, cK);   // C[h][s]
        cV = mfma16(e, wv[ks], cV);   // C[s][h]
      }
      const int s  = half * 64 + st * 16 + l15;       // K: n=s per-lane col
      const int h0 = ct * 16 + g4 * 4;                //    m=h rows (packed pair-write)
      u32x2 dk = { cvt2(cK[0], cK[1]), cvt2(cK[2], cK[3]) };
      *(u32x2*)(Kb + (s << 7) + ((((h0 >> 3) ^ (s & 7))) << 4) + ((h0 & 7) << 1)) = dk;
      const int s0 = half * 64 + st * 16 + g4 * 4;    // V^T: m=s packed, n=h col
      const int h  = ct * 16 + l15;
      u32x2 dv = { cvt2(cV[0], cV[1]), cvt2(cV[2], cV[3]) };
      *(u32x2*)(Vb + (h << 8) + ((((s0 >> 3) ^ (h & 7))) << 4) + ((s0 & 7) << 1)) = dv;
    }
  };

  stage_write();                   // src half A -> EMB
  if (tid < 128) BIAS[tid] = biasv;
  __syncthreads();                 // B1: EMB(A) ready
  stage_load(srcb + 8192);         // half B loads in flight over projKV(0)
  projKV(0);
  __syncthreads();                 // B2: EMB(A) reads done
  stage_write();                   // src half B -> EMB
  __syncthreads();                 // B3: EMB(B) ready
  projKV(1);
  __syncthreads();                 // B4: Kb/Vb/BIAS visible block-wide
  // ---- free-run tail (R8, proven): no more barriers ----

  // C-frag -> B-frag redistribution (double-pull + consumer-side select).
  // Consumer (g4,l15) word m of step ks needs h(s) = ks*32+g4*8+2m+{0,1}, held
  // by producer lane (2*(g4&1)+(m>>1))*16+l15 in word [4ks + 2*(g4>>1)+(m&1)].
  const int hi2 = g4 >> 1;
  const int sA  = ((g4 & 1) * 2) * 16 + l15;  // src lane for words m=0,1
  const int sB  = sA + 16;                    // src lane for words m=2,3

  u32x4 qB[2];
#pragma unroll
  for (int ks = 0; ks < 2; ++ks) {
    uint32_t a0 = (uint32_t)__shfl((int)qp[4 * ks + 0], sA);
    uint32_t a1 = (uint32_t)__shfl((int)qp[4 * ks + 1], sA);
    uint32_t a2 = (uint32_t)__shfl((int)qp[4 * ks + 2], sA);
    uint32_t a3 = (uint32_t)__shfl((int)qp[4 * ks + 3], sA);
    uint32_t b0 = (uint32_t)__shfl((int)qp[4 * ks + 0], sB);
    uint32_t b1 = (uint32_t)__shfl((int)qp[4 * ks + 1], sB);
    uint32_t b2 = (uint32_t)__shfl((int)qp[4 * ks + 2], sB);
    uint32_t b3 = (uint32_t)__shfl((int)qp[4 * ks + 3], sB);
    qB[ks][0] = hi2 ? a2 : a0;
    qB[ks][1] = hi2 ? a3 : a1;
    qB[ks][2] = hi2 ? b2 : b0;
    qB[ks][3] = hi2 ? b3 : b1;
  }

  // S^T = K @ Q^T : per lane col t = 16w+l15, rows s = mt*16+g4*4+r
  f32x4 sacc[8];
#pragma unroll
  for (int mt = 0; mt < 8; ++mt) sacc[mt] = {0, 0, 0, 0};
  __builtin_amdgcn_s_setprio(1);
#pragma unroll
  for (int mt = 0; mt < 8; ++mt) {
    const int srow = mt * 16 + l15;
    u32x4 k0 = *(const u32x4*)(Kb + (srow << 7) + (((g4 ^ (srow & 7))) << 4));
    u32x4 k1 = *(const u32x4*)(Kb + (srow << 7) + ((((4 + g4) ^ (srow & 7))) << 4));
    sacc[mt] = mfma16(k0, qB[0], sacc[mt]);
    sacc[mt] = mfma16(k1, qB[1], sacc[mt]);
  }
  __builtin_amdgcn_s_setprio(0);

  // softmax over s (32 s-values/lane; reduce across 4-lane group)
  float m = -3.0e38f;
#pragma unroll
  for (int mt = 0; mt < 8; ++mt) {
    f32x4 b4 = *(const f32x4*)(BIAS + mt * 16 + g4 * 4);
#pragma unroll
    for (int r = 0; r < 4; ++r) {
      float v = sacc[mt][r] * 0.125f + b4[r];  // scale = H^-0.5 ; pad bias -1e30
      sacc[mt][r] = v;
      m = fmaxf(m, v);
    }
  }
  m = fmaxf(m, __shfl_xor(m, 16));
  m = fmaxf(m, __shfl_xor(m, 32));
  float sum = 0.0f;
#pragma unroll
  for (int mt = 0; mt < 8; ++mt) {
#pragma unroll
    for (int r = 0; r < 4; ++r) {
      const int s = mt * 16 + g4 * 4 + r;
      float p = __expf(sacc[mt][r] - m);
      p = (s <= tq) ? p : 0.0f;               // causal, multiplicative
      sacc[mt][r] = p;
      sum += p;
    }
  }
  sum += __shfl_xor(sum, 16);
  sum += __shfl_xor(sum, 32);
  const float inv = 1.0f / sum;  // >0: col 0 always valid & causal-visible

  // pack P (unnormalized, <=1): sp[2mt+p] = bf16x2 of P^T[s=mt*16+g4*4+2p+{0,1}][t]
  uint32_t sp[16];
#pragma unroll
  for (int mt = 0; mt < 8; ++mt) {
    sp[2 * mt]     = cvt2(sacc[mt][0], sacc[mt][1]);
    sp[2 * mt + 1] = cvt2(sacc[mt][2], sacc[mt][3]);
  }

  // OUT^T = V^T @ P^T : A = V^T from Vb rows, B = P via double-pull shuffles
  f32x4 oacc[4];
#pragma unroll
  for (int vt = 0; vt < 4; ++vt) oacc[vt] = {0, 0, 0, 0};
  __builtin_amdgcn_s_setprio(1);
#pragma unroll
  for (int ks = 0; ks < 4; ++ks) {
    uint32_t a0 = (uint32_t)__shfl((int)sp[4 * ks + 0], sA);
    uint32_t a1 = (uint32_t)__shfl((int)sp[4 * ks + 1], sA);
    uint32_t a2 = (uint32_t)__shfl((int)sp[4 * ks + 2], sA);
    uint32_t a3 = (uint32_t)__shfl((int)sp[4 * ks + 3], sA);
    uint32_t b0 = (uint32_t)__shfl((int)sp[4 * ks + 0], sB);
    uint32_t b1 = (uint32_t)__shfl((int)sp[4 * ks + 1], sB);
    uint32_t b2 = (uint32_t)__shfl((int)sp[4 * ks + 2], sB);
    uint32_t b3 = (uint32_t)__shfl((int)sp[4 * ks + 3], sB);
    u32x4 pb;
    pb[0] = hi2 ? a2 : a0;
    pb[1] = hi2 ? a3 : a1;
    pb[2] = hi2 ? b2 : b0;
    pb[3] = hi2 ? b3 : b1;
#pragma unroll
    for (int vt = 0; vt < 4; ++vt) {
      const int vrow = vt * 16 + l15;
      u32x4 vf = *(const u32x4*)(Vb + (vrow << 8) + ((((ks * 4 + g4) ^ (vrow & 7))) << 4));
      oacc[vt] = mfma16(vf, pb, oacc[vt]);
    }
  }
  __builtin_amdgcn_s_setprio(0);

  // epilogue: out[t][h], t = 16w + l15, h = vt*16 + g4*4 + r ; fold 1/sum
  float* const ob = out + (size_t)b * 8192 + (size_t)tq * 64;
#pragma unroll
  for (int vt = 0; vt < 4; ++vt) {
    f32x4 o = { oacc[vt][0] * inv, oacc[vt][1] * inv,
                oacc[vt][2] * inv, oacc[vt][3] * inv };
    *(f32x4*)(ob + vt * 16 + g4 * 4) = o;
  }
}

extern "C" void kernel_launch(void* const* d_in, const int* in_sizes, int n_in,
                              void* d_out, int out_size, void* d_ws, size_t ws_size,
                              hipStream_t stream) {
  const float* src = (const float*)d_in[0];
  const float* tgt = (const float*)d_in[1];
  const void*  msk = d_in[2];
  const float* Wq  = (const float*)d_in[3];
  const float* Wk  = (const float*)d_in[4];
  const float* Wv  = (const float*)d_in[5];
  uint32_t* ws = (uint32_t*)d_ws;  // 48KB W frags + mask-dtype flag
  float* out = (float*)d_out;
  const int B = in_sizes[0] / (128 * 128);

  hipLaunchKernelGGL(prep_w, dim3(49), dim3(64), 0, stream, Wq, Wk, Wv, msk, ws);
  hipLaunchKernelGGL(attn_fused, dim3(B), dim3(512), 0, stream,
                     src, tgt, msk, ws, out);
}

// Round 11
// 150.574 us; speedup vs baseline: 1.4435x; 1.0236x over previous
//
#include <hip/hip_runtime.h>
#include <stdint.h>

// Fused attention head: out = softmax(mask((Tgt@Wq)(Src@Wk)^T * H^-0.5)) @ (Src@Wv)
// B=4096, T=128, C=128, H=64. One block/batch, 512 threads (8 waves).
// R11 = R10 front (4 barriers, src-only staging, Q direct from global) +
// R5-style wave-private LDS-bounce tail (Q via 2KB EMB slice, P via 4KB
// EMB+Kb slice after a post-QK barrier) replacing the 48-shuffle tail.

typedef uint32_t u32x2 __attribute__((ext_vector_type(2)));
typedef uint32_t u32x4 __attribute__((ext_vector_type(4)));
typedef float    f32x4 __attribute__((ext_vector_type(4)));
typedef __bf16   bf16x8 __attribute__((ext_vector_type(8)));

static __device__ __forceinline__ uint32_t pack2(float a, float b) {  // RNE (prep kernel)
  uint32_t ua = __builtin_bit_cast(uint32_t, a);
  uint32_t ub = __builtin_bit_cast(uint32_t, b);
  ua += 0x7FFFu + ((ua >> 16) & 1u);
  ub += 0x7FFFu + ((ub >> 16) & 1u);
  return (ua >> 16) | (ub & 0xFFFF0000u);
}
// compiler-generated f32->bf16 RNE pair (HW-proven R9/R10)
static __device__ __forceinline__ uint32_t cvt2(float a, float b) {
  uint16_t lo = __builtin_bit_cast(uint16_t, (__bf16)a);
  uint16_t hi = __builtin_bit_cast(uint16_t, (__bf16)b);
  return (uint32_t)lo | ((uint32_t)hi << 16);
}
static __device__ __forceinline__ f32x4 mfma16(u32x4 a, u32x4 b, f32x4 c) {
  return __builtin_amdgcn_mfma_f32_16x16x32_bf16(
      __builtin_bit_cast(bf16x8, a), __builtin_bit_cast(bf16x8, b), c, 0, 0, 0);
}

// ---- prep: pack Wq/Wk/Wv into MFMA frag layout in ws; detect mask dtype ----
// frag f=(m*4+ct)*4+ks, lane l: 8 bf16 of W[c][h], h=ct*16+(l&15), c=ks*32+(l>>4)*8+0..7.
// Serves BOTH as B-frag of W (V proj) and A-frag of W^T (K/Q proj).
__global__ void prep_w(const float* __restrict__ Wq, const float* __restrict__ Wk,
                       const float* __restrict__ Wv, const void* __restrict__ mask,
                       uint32_t* __restrict__ ws) {
  const int blk = blockIdx.x;
  const int l = threadIdx.x;  // 0..63
  if (blk < 48) {
    const int m  = blk >> 4;
    const int ct = (blk >> 2) & 3;
    const int ks = blk & 3;
    const float* W = (m == 0) ? Wq : ((m == 1) ? Wk : Wv);
    const int h  = ct * 16 + (l & 15);
    const int c0 = ks * 32 + (l >> 4) * 8;
    u32x4 v;
#pragma unroll
    for (int p = 0; p < 4; ++p)
      v[p] = pack2(W[(c0 + 2 * p) * 64 + h], W[(c0 + 2 * p + 1) * 64 + h]);
    ((u32x4*)ws)[blk * 64 + l] = v;
  } else {
    // mask dtype detect: 0=int32(0/1), 1=bytes, 2=float
    const uint32_t* mw = (const uint32_t*)mask;
    int fl = 0;
    for (int i = l * 16; i < l * 16 + 16; ++i) {
      uint32_t x = mw[i];
      if (x == 0x3F800000u) fl = 2;
      else if (x > 1u && fl != 2) fl = 1;
    }
#pragma unroll
    for (int off = 32; off > 0; off >>= 1) {
      int o = __shfl_down(fl, off);
      fl = (o > fl) ? o : fl;
    }
    if (l == 0) ws[12288] = (uint32_t)fl;
  }
}

// LDS (48.5 KB):
//  EMB [64][128] bf16 swz (16K)  src staging; tail: wave-private Q (2KB/wave),
//                                then P rows tl 0..7
//  Kb  [128][64] bf16 swz (16K)  K[s][h]; tail (after B5): P rows tl 8..15
//  Vb  [64][128] bf16 swz (16K)  V^T[h][s]
//  BIAS[128] f32
// Swizzle: 16B chunk c of row r stored at chunk (c ^ (r&7)); Q/P slices use
// full-row XOR (c ^ l15-based) as derived per-slice.
__global__ __launch_bounds__(512, 3) void attn_fused(
    const float* __restrict__ src, const float* __restrict__ tgt,
    const void* __restrict__ mask, const uint32_t* __restrict__ ws,
    float* __restrict__ out) {
  __shared__ __align__(16) uint8_t lds[49664];
  uint8_t* const EMB = lds;
  uint8_t* const Kb  = lds + 16384;
  uint8_t* const Vb  = lds + 32768;
  float*  const BIAS = (float*)(lds + 49152);

  const int b   = blockIdx.x;
  const int tid = (int)threadIdx.x;
  const int l   = tid & 63;
  const int w   = tid >> 6;      // wave 0..7
  const int l15 = l & 15;
  const int g4  = l >> 4;        // 0..3
  const int ct  = w & 3;         // wave's h-tile for K/V projections
  const int sg  = (w >> 2) * 2;  // wave's first local row-tile for K/V (0 or 2)
  const int tq  = 16 * w + l15;  // this lane's output row t

  const u32x4* wsv = (const u32x4*)ws;
  const int mflag = (int)ws[12288];
  const float* const srcb = src + (size_t)b * 16384;
  const float* const tgtb = tgt + (size_t)b * 16384;

  // ---- issue longest-latency loads FIRST ----
  // Q A-frag rows: lane needs tgt[tq][ks*32 + g4*8 + 0..7] for ks=0..3
  f32x4 qv[8];
  {
    const float* pq = tgtb + tq * 128 + g4 * 8;
#pragma unroll
    for (int ks = 0; ks < 4; ++ks) {
      qv[2 * ks]     = *(const f32x4*)(pq + ks * 32);
      qv[2 * ks + 1] = *(const f32x4*)(pq + ks * 32 + 4);
    }
  }
  // src half A staging loads
  f32x4 pf[4];
  auto stage_load = [&](const float* gbase) {
#pragma unroll
    for (int p = 0; p < 4; ++p)
      pf[p] = *(const f32x4*)(gbase + tid * 4 + p * 2048);
  };
  stage_load(srcb);
  // pad-mask bias
  float biasv = 0.0f;
  if (tid < 128) {
    bool valid;
    if (mflag == 1)      valid = ((const uint8_t*)mask)[b * 128 + tid] != 0;
    else if (mflag == 0) valid = ((const int*)mask)[b * 128 + tid] != 0;
    else                 valid = ((const float*)mask)[b * 128 + tid] != 0.0f;
    biasv = valid ? 0.0f : -1e30f;
  }

  // ---- projQ (consumer-aligned, from global): all 64 h for own t-tile ----
  // qp[ctq*2+p] = bf16x2 of Q^T[h = ctq*16 + g4*4 + 2p + {0,1}][t]
  uint32_t qp[8];
  {
    f32x4 c0 = {0,0,0,0}, c1 = {0,0,0,0}, c2 = {0,0,0,0}, c3 = {0,0,0,0};
#pragma unroll
    for (int ks = 0; ks < 4; ++ks) {
      u32x4 e = { cvt2(qv[2*ks][0], qv[2*ks][1]), cvt2(qv[2*ks][2], qv[2*ks][3]),
                  cvt2(qv[2*ks+1][0], qv[2*ks+1][1]), cvt2(qv[2*ks+1][2], qv[2*ks+1][3]) };
      c0 = mfma16(wsv[(0  + ks) * 64 + l], e, c0);
      c1 = mfma16(wsv[(4  + ks) * 64 + l], e, c1);
      c2 = mfma16(wsv[(8  + ks) * 64 + l], e, c2);
      c3 = mfma16(wsv[(12 + ks) * 64 + l], e, c3);
    }
    qp[0] = cvt2(c0[0], c0[1]); qp[1] = cvt2(c0[2], c0[3]);
    qp[2] = cvt2(c1[0], c1[1]); qp[3] = cvt2(c1[2], c1[3]);
    qp[4] = cvt2(c2[0], c2[1]); qp[5] = cvt2(c2[2], c2[3]);
    qp[6] = cvt2(c3[0], c3[1]); qp[7] = cvt2(c3[2], c3[3]);
  }

  // ---- staged K/V pipeline (R10 front) ----
  auto stage_write = [&]() {
#pragma unroll
    for (int p = 0; p < 4; ++p) {
      const int c   = tid + p * 512;
      const int row = c >> 5;     // 0..63
      const int cc  = c & 31;     // f32x4 chunk within row
      u32x2 d = { cvt2(pf[p][0], pf[p][1]), cvt2(pf[p][2], pf[p][3]) };
      *(u32x2*)(EMB + (row << 8) + ((((cc >> 1) ^ (row & 7))) << 4) + ((cc & 1) << 3)) = d;
    }
  };
  u32x4 wk[4], wv[4];
#pragma unroll
  for (int ks = 0; ks < 4; ++ks) {
    wk[ks] = wsv[((4 + ct) * 4 + ks) * 64 + l];   // A-frag of Wk^T
    wv[ks] = wsv[((8 + ct) * 4 + ks) * 64 + l];   // B-frag of Wv
  }
  auto projKV = [&](int half) {
#pragma unroll
    for (int i = 0; i < 2; ++i) {
      const int st  = sg + i;            // local 16-row tile 0..3
      const int row = st * 16 + l15;     // EMB row
      f32x4 cK = {0, 0, 0, 0}, cV = {0, 0, 0, 0};
#pragma unroll
      for (int ks = 0; ks < 4; ++ks) {
        u32x4 e = *(const u32x4*)(EMB + (row << 8) + ((((ks * 4 + g4) ^ (row & 7))) << 4));
        cK = mfma16(wk[ks], e, cK);   // C[h][s]
        cV = mfma16(e, wv[ks], cV);   // C[s][h]
      }
      const int s  = half * 64 + st * 16 + l15;       // K: n=s per-lane col
      const int h0 = ct * 16 + g4 * 4;                //    m=h rows (packed pair-write)
      u32x2 dk = { cvt2(cK[0], cK[1]), cvt2(cK[2], cK[3]) };
      *(u32x2*)(Kb + (s << 7) + ((((h0 >> 3) ^ (s & 7))) << 4) + ((h0 & 7) << 1)) = dk;
      const int s0 = half * 64 + st * 16 + g4 * 4;    // V^T: m=s packed, n=h col
      const int h  = ct * 16 + l15;
      u32x2 dv = { cvt2(cV[0], cV[1]), cvt2(cV[2], cV[3]) };
      *(u32x2*)(Vb + (h << 8) + ((((s0 >> 3) ^ (h & 7))) << 4) + ((s0 & 7) << 1)) = dv;
    }
  };

  stage_write();                   // src half A -> EMB
  if (tid < 128) BIAS[tid] = biasv;
  __syncthreads();                 // B1: EMB(A) ready
  stage_load(srcb + 8192);         // half B loads in flight over projKV(0)
  projKV(0);
  __syncthreads();                 // B2: EMB(A) reads done
  stage_write();                   // src half B -> EMB
  __syncthreads();                 // B3: EMB(B) ready
  projKV(1);
  __syncthreads();                 // B4: Kb/Vb/BIAS ready; EMB dead

  // ---- Q bounce: wave-private [16 t][64 h] bf16 slice in EMB (2KB/wave) ----
  // write: qp[2ctq..] (h = ctq*16+g4*4+0..3) at chunk (ctq*2+(g4>>1))^(l15&7),
  //        half g4&1;  read B-frag: 16B at chunk (ks*4+g4)^(l15&7).
  uint8_t* const Qw = EMB + (w << 11) + (l15 << 7);
#pragma unroll
  for (int ctq = 0; ctq < 4; ++ctq) {
    u32x2 dq = { qp[2 * ctq], qp[2 * ctq + 1] };
    const int cw = ctq * 2 + (g4 >> 1);
    *(u32x2*)(Qw + (((cw ^ (l15 & 7))) << 4) + ((g4 & 1) << 3)) = dq;
  }
  u32x4 qB[2];
#pragma unroll
  for (int ks = 0; ks < 2; ++ks)
    qB[ks] = *(const u32x4*)(Qw + ((((ks * 4 + g4) ^ (l15 & 7))) << 4));

  // ---- S^T = K @ Q^T : per lane col t = 16w+l15, rows s = mt*16+g4*4+r ----
  f32x4 sacc[8];
#pragma unroll
  for (int mt = 0; mt < 8; ++mt) sacc[mt] = {0, 0, 0, 0};
  __builtin_amdgcn_s_setprio(1);
#pragma unroll
  for (int mt = 0; mt < 8; ++mt) {
    const int srow = mt * 16 + l15;
    u32x4 k0 = *(const u32x4*)(Kb + (srow << 7) + (((g4 ^ (srow & 7))) << 4));
    u32x4 k1 = *(const u32x4*)(Kb + (srow << 7) + ((((4 + g4) ^ (srow & 7))) << 4));
    sacc[mt] = mfma16(k0, qB[0], sacc[mt]);
    sacc[mt] = mfma16(k1, qB[1], sacc[mt]);
  }
  __builtin_amdgcn_s_setprio(0);

  __syncthreads();                 // B5: all QK reads of Kb done -> Kb reusable

  // ---- softmax over s (32 s-values/lane; reduce across 4-lane group) ----
  float m = -3.0e38f;
#pragma unroll
  for (int mt = 0; mt < 8; ++mt) {
    f32x4 b4 = *(const f32x4*)(BIAS + mt * 16 + g4 * 4);
#pragma unroll
    for (int r = 0; r < 4; ++r) {
      float v = sacc[mt][r] * 0.125f + b4[r];  // scale = H^-0.5 ; pad bias -1e30
      sacc[mt][r] = v;
      m = fmaxf(m, v);
    }
  }
  m = fmaxf(m, __shfl_xor(m, 16));
  m = fmaxf(m, __shfl_xor(m, 32));
  float sum = 0.0f;
#pragma unroll
  for (int mt = 0; mt < 8; ++mt) {
#pragma unroll
    for (int r = 0; r < 4; ++r) {
      const int s = mt * 16 + g4 * 4 + r;
      float p = __expf(sacc[mt][r] - m);
      p = (s <= tq) ? p : 0.0f;               // causal, multiplicative
      sacc[mt][r] = p;
      sum += p;
    }
  }
  sum += __shfl_xor(sum, 16);
  sum += __shfl_xor(sum, 32);
  const float inv = 1.0f / sum;  // >0: col 0 always valid & causal-visible

  // ---- P bounce: wave-private [16 t][128 s] slice in EMB(tl<8)+Kb(tl>=8) ----
  // (R5-proven formulas) write chunk (mt*2+(g4>>1))^l15, half g4&1;
  // read 16B at chunk (ks*4+g4)^l15. In-wave W->R ordering: compiler (R1-proven).
  uint8_t* const Pr = (l15 < 8) ? (EMB + (w << 11) + (l15 << 8))
                                : (Kb + (w << 11) + ((l15 - 8) << 8));
#pragma unroll
  for (int mt = 0; mt < 8; ++mt) {
    u32x2 d = { cvt2(sacc[mt][0], sacc[mt][1]), cvt2(sacc[mt][2], sacc[mt][3]) };
    const int c = mt * 2 + (g4 >> 1);
    *(u32x2*)(Pr + (((c ^ l15)) << 4) + ((g4 & 1) << 3)) = d;
  }

  // ---- OUT^T = V^T @ P^T : A = V^T from Vb rows, B = P from own slice ----
  f32x4 oacc[4];
#pragma unroll
  for (int vt = 0; vt < 4; ++vt) oacc[vt] = {0, 0, 0, 0};
  __builtin_amdgcn_s_setprio(1);
#pragma unroll
  for (int ks = 0; ks < 4; ++ks) {
    u32x4 pb = *(const u32x4*)(Pr + ((((ks * 4 + g4) ^ l15)) << 4));
#pragma unroll
    for (int vt = 0; vt < 4; ++vt) {
      const int vrow = vt * 16 + l15;
      u32x4 vf = *(const u32x4*)(Vb + (vrow << 8) + ((((ks * 4 + g4) ^ (vrow & 7))) << 4));
      oacc[vt] = mfma16(vf, pb, oacc[vt]);
    }
  }
  __builtin_amdgcn_s_setprio(0);

  // epilogue: out[t][h], t = 16w + l15, h = vt*16 + g4*4 + r ; fold 1/sum
  float* const ob = out + (size_t)b * 8192 + (size_t)tq * 64;
#pragma unroll
  for (int vt = 0; vt < 4; ++vt) {
    f32x4 o = { oacc[vt][0] * inv, oacc[vt][1] * inv,
                oacc[vt][2] * inv, oacc[vt][3] * inv };
    *(f32x4*)(ob + vt * 16 + g4 * 4) = o;
  }
}

extern "C" void kernel_launch(void* const* d_in, const int* in_sizes, int n_in,
                              void* d_out, int out_size, void* d_ws, size_t ws_size,
                              hipStream_t stream) {
  const float* src = (const float*)d_in[0];
  const float* tgt = (const float*)d_in[1];
  const void*  msk = d_in[2];
  const float* Wq  = (const float*)d_in[3];
  const float* Wk  = (const float*)d_in[4];
  const float* Wv  = (const float*)d_in[5];
  uint32_t* ws = (uint32_t*)d_ws;  // 48KB W frags + mask-dtype flag
  float* out = (float*)d_out;
  const int B = in_sizes[0] / (128 * 128);

  hipLaunchKernelGGL(prep_w, dim3(49), dim3(64), 0, stream, Wq, Wk, Wv, msk, ws);
  hipLaunchKernelGGL(attn_fused, dim3(B), dim3(512), 0, stream,
                     src, tgt, msk, ws, out);
}